// Round 6
// baseline (100.209 us; speedup 1.0000x reference)
//
#include <hip/hip_runtime.h>
#include <math.h>

#define NUM_E 6
#define DIM 1024
#define HID 256
#define NTOK 32768
#define NPB 4096   // tokens per batch (N)
#define TTYPE_UNKNOWN 5
#define ONE_MINUS_ALPHA 0.775f
#define FLOOR_TERM 0.0375f     // alpha * (1/E)
#define GRP 4                  // tokens per hidden block (1366 working blocks)

// workspace layout (bytes)
#define WS_CNT   0
#define WS_LIST  256                                  // 32768 * 4 = 131072
#define WS_H     (256 * 1024)                         // gelu(h): NTOK x HID fp32
#define WS_NEED  ((size_t)WS_H + (size_t)NTOK * HID * 4)

// Closed-form top1 + hard-cap + combine for a probs vector of 6.
__device__ __forceinline__ void finalize_and_write(const float probs[NUM_E], float cap,
                                                   float* __restrict__ disp_out,
                                                   float* __restrict__ comb_out) {
    float v = probs[0];
    int bi = 0;
#pragma unroll
    for (int e = 1; e < NUM_E; ++e) {
        if (probs[e] > v) { v = probs[e]; bi = e; }
    }
    float excess = fmaxf(v - cap, 0.0f);
    float capped = v - excess;                 // min(v, cap)
    float hr_idx = fmaxf(cap - capped, 0.0f);
    float hsum = fmaxf(hr_idx + 5.0f * cap, 1e-8f);
    float disp[NUM_E];
    float other = excess * cap / hsum;
#pragma unroll
    for (int e = 0; e < NUM_E; ++e) disp[e] = other;
    disp[bi] = capped + excess * hr_idx / hsum;
    float s = 0.0f;
#pragma unroll
    for (int e = 0; e < NUM_E; ++e) s += disp[e];
    float inv = 1.0f / (s + 1e-8f);
#pragma unroll
    for (int e = 0; e < NUM_E; ++e) {
        disp_out[e] = disp[e];
        comb_out[e] = disp[e] * inv;
    }
}

// Known tokens -> final output directly; unknown -> compacted list.
__launch_bounds__(256)
__global__ void classify_kernel(const int* __restrict__ ttypes,
                                const int* __restrict__ tarr,
                                const float* __restrict__ base,
                                float* __restrict__ out,
                                int* __restrict__ cnt,
                                int* __restrict__ list) {
    int i = blockIdx.x * blockDim.x + threadIdx.x;
    if (i >= NTOK) return;
    int ty = ttypes[i];
    if (ty == TTYPE_UNKNOWN) {
        int pos = atomicAdd(cnt, 1);
        list[pos] = i;
        return;
    }
    int b = i / NPB;
    float tnorm = (float)tarr[b] / 1000.0f;
    float cap = 0.5f + 1.1f * tnorm;
    float probs[NUM_E];
#pragma unroll
    for (int e = 0; e < NUM_E; ++e)
        probs[e] = ONE_MINUS_ALPHA * base[ty * NUM_E + e] + FLOOR_TERM;
    finalize_and_write(probs, cap,
                       out + (size_t)i * NUM_E,
                       out + (size_t)NTOK * NUM_E + (size_t)i * NUM_E);
}

// Layer 1 for unknown tokens. Block = 4 tokens x 256 cols, 256 threads.
// x rows staged once in 16 KB LDS (barrier-free K-loop, broadcast b128 reads);
// thread tid owns col tid; W1 coalesced with explicit next-step prefetch;
// float2 accumulators (even/odd k split) for packed-FMA codegen.
__launch_bounds__(256)
__global__ void hidden_kernel(const float* __restrict__ tokens,
                              const float* __restrict__ W1,
                              const float* __restrict__ b1,
                              float* __restrict__ hbuf,
                              const int* __restrict__ cnt,
                              const int* __restrict__ list) {
    __shared__ float xs[GRP][DIM];       // 16 KB

    int count = cnt[0];
    int start = blockIdx.x * GRP;
    if (count == 0 || start >= count) return;
    int tid = threadIdx.x;

    int idxs[GRP];
#pragma unroll
    for (int r = 0; r < GRP; ++r) {
        int idx = start + r;
        if (idx > count - 1) idx = count - 1;   // duplicate tail -> idempotent writes
        idxs[r] = idx;
        int tok = list[idx];
        const float4* src = reinterpret_cast<const float4*>(tokens + (size_t)tok * DIM);
        reinterpret_cast<float4*>(xs[r])[tid] = src[tid];
    }
    __syncthreads();

    float2 acc[GRP];
#pragma unroll
    for (int r = 0; r < GRP; ++r) acc[r] = make_float2(0.0f, 0.0f);

    const float* w1p = W1 + tid;        // col = tid
    float wc0 = w1p[0 * HID];
    float wc1 = w1p[1 * HID];
    float wc2 = w1p[2 * HID];
    float wc3 = w1p[3 * HID];

#pragma unroll 1
    for (int k = 0; k < DIM; k += 4) {
        int kn = (k + 4 < DIM) ? (k + 4) : k;   // clamp: last iter re-reads (harmless)
        float wn0 = w1p[(kn + 0) * HID];
        float wn1 = w1p[(kn + 1) * HID];
        float wn2 = w1p[(kn + 2) * HID];
        float wn3 = w1p[(kn + 3) * HID];
        float2 wlo = make_float2(wc0, wc1);
        float2 whi = make_float2(wc2, wc3);
#pragma unroll
        for (int r = 0; r < GRP; ++r) {
            float4 xq = *reinterpret_cast<const float4*>(&xs[r][k]);  // broadcast b128
            float2 xlo = make_float2(xq.x, xq.y);
            float2 xhi = make_float2(xq.z, xq.w);
            acc[r].x = fmaf(xlo.x, wlo.x, acc[r].x);
            acc[r].y = fmaf(xlo.y, wlo.y, acc[r].y);
            acc[r].x = fmaf(xhi.x, whi.x, acc[r].x);
            acc[r].y = fmaf(xhi.y, whi.y, acc[r].y);
        }
        wc0 = wn0; wc1 = wn1; wc2 = wn2; wc3 = wn3;
    }

    // exact GELU: x * 0.5 * (1 + erf(x/sqrt(2)))
    float bj = b1[tid];
    const float kc = 0.70710678118654752f;
#pragma unroll
    for (int r = 0; r < GRP; ++r) {
        float pre = acc[r].x + acc[r].y + bj;
        hbuf[(size_t)idxs[r] * HID + tid] = 0.5f * pre * (1.0f + erff(pre * kc));
    }
}

// Layer 2 + finalize. Block = 6 waves; wave e computes logit[slot][e] for 64 slots.
__launch_bounds__(384)
__global__ void out_kernel(const float* __restrict__ hbuf,
                           const float* __restrict__ W2,
                           const float* __restrict__ b2,
                           const int* __restrict__ tarr,
                           float* __restrict__ out,
                           const int* __restrict__ cnt,
                           const int* __restrict__ list) {
    __shared__ float w2s[HID * NUM_E];
    __shared__ float ls[64][NUM_E];
    int count = cnt[0];
    int g = blockIdx.x;
    if (count == 0 || g * 64 >= count) return;
    int tid = threadIdx.x;
    for (int kk = tid; kk < HID * NUM_E; kk += 384) w2s[kk] = W2[kk];
    __syncthreads();

    int lane = tid & 63;
    int e = tid >> 6;                   // 0..5
    int idx = g * 64 + lane;
    if (idx > count - 1) idx = count - 1;
    const float* hrow = hbuf + (size_t)idx * HID;
    float acc = 0.0f;
    for (int j = 0; j < HID; j += 4) {
        float4 hq = *reinterpret_cast<const float4*>(hrow + j);
        acc = fmaf(hq.x, w2s[(j + 0) * NUM_E + e], acc);
        acc = fmaf(hq.y, w2s[(j + 1) * NUM_E + e], acc);
        acc = fmaf(hq.z, w2s[(j + 2) * NUM_E + e], acc);
        acc = fmaf(hq.w, w2s[(j + 3) * NUM_E + e], acc);
    }
    ls[lane][e] = (acc + b2[e]) / 0.1f;   // temperature
    __syncthreads();

    if (tid < 64) {
        int tokidx = list[idx];
        int b = tokidx / NPB;
        float tnorm = (float)tarr[b] / 1000.0f;
        float cap = 0.5f + 1.1f * tnorm;
        float probs[NUM_E];
#pragma unroll
        for (int ee = 0; ee < NUM_E; ++ee)
            probs[ee] = ONE_MINUS_ALPHA * ls[lane][ee] + FLOOR_TERM;
        finalize_and_write(probs, cap,
                           out + (size_t)tokidx * NUM_E,
                           out + (size_t)NTOK * NUM_E + (size_t)tokidx * NUM_E);
    }
}

// Fallback (ws too small): round-5 fused MLP, 8 tokens/block (proven 96 us).
#define FGRP 8
__launch_bounds__(256)
__global__ void mlp_fallback(const float* __restrict__ tokens,
                             const int* __restrict__ tarr,
                             const float* __restrict__ W1,
                             const float* __restrict__ b1,
                             const float* __restrict__ W2,
                             const float* __restrict__ b2,
                             float* __restrict__ out,
                             const int* __restrict__ cnt,
                             const int* __restrict__ list) {
    __shared__ float xs[FGRP][DIM];
    __shared__ float hs[FGRP][HID + 1];
    __shared__ float w2s[HID * NUM_E];
    __shared__ float ls[FGRP][NUM_E];
    int count = cnt[0];
    int start = blockIdx.x * FGRP;
    if (count == 0 || start >= count) return;
    int tid = threadIdx.x;
    for (int k = tid; k < HID * NUM_E; k += 256) w2s[k] = W2[k];
    int toks[FGRP];
#pragma unroll
    for (int r = 0; r < FGRP; ++r) {
        int idx = start + r;
        if (idx > count - 1) idx = count - 1;
        toks[r] = list[idx];
        const float4* src = reinterpret_cast<const float4*>(tokens + (size_t)toks[r] * DIM);
        reinterpret_cast<float4*>(xs[r])[tid] = src[tid];
    }
    __syncthreads();
    float acc[FGRP];
#pragma unroll
    for (int r = 0; r < FGRP; ++r) acc[r] = 0.0f;
    const float* w1p = W1 + tid;
#pragma unroll 2
    for (int k = 0; k < DIM; k += 4) {
        float w0 = w1p[(k + 0) * HID];
        float w1_ = w1p[(k + 1) * HID];
        float w2_ = w1p[(k + 2) * HID];
        float w3_ = w1p[(k + 3) * HID];
#pragma unroll
        for (int r = 0; r < FGRP; ++r) {
            float4 xq = *reinterpret_cast<const float4*>(&xs[r][k]);
            acc[r] = fmaf(xq.x, w0, acc[r]);
            acc[r] = fmaf(xq.y, w1_, acc[r]);
            acc[r] = fmaf(xq.z, w2_, acc[r]);
            acc[r] = fmaf(xq.w, w3_, acc[r]);
        }
    }
    float bj = b1[tid];
#pragma unroll
    for (int r = 0; r < FGRP; ++r) {
        float pre = acc[r] + bj;
        hs[r][tid] = 0.5f * pre * (1.0f + erff(pre * 0.70710678118654752f));
    }
    __syncthreads();
    if (tid < FGRP * NUM_E) {
        int r = tid / NUM_E, e = tid % NUM_E;
        float s = 0.0f;
        for (int j = 0; j < HID; ++j) s = fmaf(hs[r][j], w2s[j * NUM_E + e], s);
        ls[r][e] = (s + b2[e]) / 0.1f;
    }
    __syncthreads();
    if (tid < FGRP && start + tid < count) {
        int tokidx = toks[tid];
        int b = tokidx / NPB;
        float tnorm = (float)tarr[b] / 1000.0f;
        float cap = 0.5f + 1.1f * tnorm;
        float probs[NUM_E];
#pragma unroll
        for (int e = 0; e < NUM_E; ++e)
            probs[e] = ONE_MINUS_ALPHA * ls[tid][e] + FLOOR_TERM;
        finalize_and_write(probs, cap,
                           out + (size_t)tokidx * NUM_E,
                           out + (size_t)NTOK * NUM_E + (size_t)tokidx * NUM_E);
    }
}

extern "C" void kernel_launch(void* const* d_in, const int* in_sizes, int n_in,
                              void* d_out, int out_size, void* d_ws, size_t ws_size,
                              hipStream_t stream) {
    const float* tokens = (const float*)d_in[0];
    const int*   ttypes = (const int*)d_in[1];
    const int*   tarr   = (const int*)d_in[2];
    const float* W1     = (const float*)d_in[3];
    const float* b1     = (const float*)d_in[4];
    const float* W2     = (const float*)d_in[5];
    const float* b2     = (const float*)d_in[6];
    const float* base   = (const float*)d_in[7];
    float* out = (float*)d_out;

    char* ws = (char*)d_ws;
    int* cnt  = (int*)(ws + WS_CNT);
    int* list = (int*)(ws + WS_LIST);

    hipMemsetAsync(cnt, 0, sizeof(int), stream);
    classify_kernel<<<NTOK / 256, 256, 0, stream>>>(ttypes, tarr, base, out, cnt, list);

    if (ws_size >= WS_NEED) {
        float* hbuf = (float*)(ws + WS_H);
        hidden_kernel<<<NTOK / GRP, 256, 0, stream>>>(tokens, W1, b1, hbuf, cnt, list);
        out_kernel<<<NTOK / 64, 384, 0, stream>>>(hbuf, W2, b2, tarr, out, cnt, list);
    } else {
        mlp_fallback<<<NTOK / FGRP, 256, 0, stream>>>(tokens, tarr, W1, b1, W2, b2,
                                                      out, cnt, list);
    }
}

// Round 8
// 88.843 us; speedup vs baseline: 1.1279x; 1.1279x over previous
//
#include <hip/hip_runtime.h>
#include <math.h>

#define NUM_E 6
#define DIM 1024
#define HID 256
#define NTOK 32768
#define NPB 4096   // tokens per batch (N)
#define TTYPE_UNKNOWN 5
#define ONE_MINUS_ALPHA 0.775f
#define FLOOR_TERM 0.0375f     // alpha * (1/E)
#define GRP 8                  // tokens per MLP block (683 working blocks; W1-reuse lever)
#define KHALF 512              // K split across thread halves

// Closed-form top1 + hard-cap + combine for a probs vector of 6.
__device__ __forceinline__ void finalize_and_write(const float probs[NUM_E], float cap,
                                                   float* __restrict__ disp_out,
                                                   float* __restrict__ comb_out) {
    float v = probs[0];
    int bi = 0;
#pragma unroll
    for (int e = 1; e < NUM_E; ++e) {
        if (probs[e] > v) { v = probs[e]; bi = e; }
    }
    float excess = fmaxf(v - cap, 0.0f);
    float capped = v - excess;                 // min(v, cap)
    float hr_idx = fmaxf(cap - capped, 0.0f);
    float hsum = fmaxf(hr_idx + 5.0f * cap, 1e-8f);
    float disp[NUM_E];
    float other = excess * cap / hsum;
#pragma unroll
    for (int e = 0; e < NUM_E; ++e) disp[e] = other;
    disp[bi] = capped + excess * hr_idx / hsum;
    float s = 0.0f;
#pragma unroll
    for (int e = 0; e < NUM_E; ++e) s += disp[e];
    float inv = 1.0f / (s + 1e-8f);
#pragma unroll
    for (int e = 0; e < NUM_E; ++e) {
        disp_out[e] = disp[e];
        comb_out[e] = disp[e] * inv;
    }
}

// Known tokens -> final output directly; unknown -> compacted list.
__launch_bounds__(256)
__global__ void classify_kernel(const int* __restrict__ ttypes,
                                const int* __restrict__ tarr,
                                const float* __restrict__ base,
                                float* __restrict__ out,
                                int* __restrict__ cnt,
                                int* __restrict__ list) {
    int i = blockIdx.x * blockDim.x + threadIdx.x;
    if (i >= NTOK) return;
    int ty = ttypes[i];
    if (ty == TTYPE_UNKNOWN) {
        int pos = atomicAdd(cnt, 1);
        list[pos] = i;
        return;
    }
    int b = i / NPB;
    float tnorm = (float)tarr[b] / 1000.0f;
    float cap = 0.5f + 1.1f * tnorm;
    float probs[NUM_E];
#pragma unroll
    for (int e = 0; e < NUM_E; ++e)
        probs[e] = ONE_MINUS_ALPHA * base[ty * NUM_E + e] + FLOOR_TERM;
    finalize_and_write(probs, cap,
                       out + (size_t)i * NUM_E,
                       out + (size_t)NTOK * NUM_E + (size_t)i * NUM_E);
}

// Fused MLP gate, 512 threads = 8 waves. GRP=8 tokens staged once in 32 KB LDS.
// Thread (col = tid&255, half = tid>>8) accumulates K-half [half*512, +512).
// Post-loop buffers alias the xs region (after a barrier) so LDS stays 32 KB
// -> 4 blocks/CU wave-capped, ~5.3 waves/SIMD.
__launch_bounds__(512)
__global__ void mlp_kernel(const float* __restrict__ tokens,
                           const int* __restrict__ tarr,
                           const float* __restrict__ W1,
                           const float* __restrict__ b1,
                           const float* __restrict__ W2,
                           const float* __restrict__ b2,
                           float* __restrict__ out,
                           const int* __restrict__ cnt,
                           const int* __restrict__ list) {
    __shared__ float smem[GRP * DIM];    // 32 KB, re-purposed after the K-loop
    float (*xs)[DIM] = (float (*)[DIM])smem;

    int count = cnt[0];
    int start = blockIdx.x * GRP;
    if (start >= count) return;
    int tid = threadIdx.x;

    // Stage 8 token rows: 512 threads -> 2 rows per pass, float4 coalesced.
    {
        int sub = tid & 255;             // float4 slot within a row
        int rh = tid >> 8;               // 0..1
#pragma unroll
        for (int rp = 0; rp < GRP; rp += 2) {
            int r = rp + rh;
            int idx = start + r;
            if (idx > count - 1) idx = count - 1;   // dup tail -> idempotent writes
            int tok = list[idx];
            const float4* src = reinterpret_cast<const float4*>(tokens + (size_t)tok * DIM);
            reinterpret_cast<float4*>(xs[r])[sub] = src[sub];
        }
    }
    __syncthreads();

    int col = tid & 255;
    int half = tid >> 8;
    int kbase = half * KHALF;

    float acc[GRP];
#pragma unroll
    for (int r = 0; r < GRP; ++r) acc[r] = 0.0f;

    const float* w1p = W1 + (size_t)kbase * HID + col;
#pragma unroll 2
    for (int k = 0; k < KHALF; k += 4) {
        float w0 = w1p[(k + 0) * HID];
        float w1_ = w1p[(k + 1) * HID];
        float w2_ = w1p[(k + 2) * HID];
        float w3_ = w1p[(k + 3) * HID];
#pragma unroll
        for (int r = 0; r < GRP; ++r) {
            float4 xq = *reinterpret_cast<const float4*>(&xs[r][kbase + k]);  // broadcast b128
            acc[r] = fmaf(xq.x, w0, acc[r]);
            acc[r] = fmaf(xq.y, w1_, acc[r]);
            acc[r] = fmaf(xq.z, w2_, acc[r]);
            acc[r] = fmaf(xq.w, w3_, acc[r]);
        }
    }
    __syncthreads();   // all xs reads done; re-purpose smem

    // aliased post-loop layout (floats): hp[8][512] @0, hs[8][257] @4096,
    // w2s[1536] @6152, ls[8][6] @7688  -> total 7736 < 8192
    float (*hp)[512] = (float (*)[512])smem;
    float (*hs)[HID + 1] = (float (*)[HID + 1])(smem + 4096);
    float* w2s = smem + 6152;
    float (*ls)[NUM_E] = (float (*)[NUM_E])(smem + 7688);

#pragma unroll
    for (int r = 0; r < GRP; ++r) hp[r][tid] = acc[r];
    for (int kk = tid; kk < HID * NUM_E; kk += 512) w2s[kk] = W2[kk];
    __syncthreads();

    // combine K-halves + exact GELU
    if (tid < 256) {
        float bj = b1[tid];
        const float kc = 0.70710678118654752f;
#pragma unroll
        for (int r = 0; r < GRP; ++r) {
            float pre = hp[r][tid] + hp[r][tid + 256] + bj;
            hs[r][tid] = 0.5f * pre * (1.0f + erff(pre * kc));
        }
    }
    __syncthreads();

    // Layer 2: 48 threads, one (token, expert) dot each
    if (tid < GRP * NUM_E) {
        int r = tid / NUM_E, e = tid % NUM_E;
        float s = 0.0f;
        for (int j = 0; j < HID; ++j) s = fmaf(hs[r][j], w2s[j * NUM_E + e], s);
        ls[r][e] = (s + b2[e]) / 0.1f;   // temperature
    }
    __syncthreads();

    // Finalize per token
    if (tid < GRP && start + tid < count) {
        int tokidx = list[start + tid];
        int b = tokidx / NPB;
        float tnorm = (float)tarr[b] / 1000.0f;
        float cap = 0.5f + 1.1f * tnorm;
        float probs[NUM_E];
#pragma unroll
        for (int e = 0; e < NUM_E; ++e)
            probs[e] = ONE_MINUS_ALPHA * ls[tid][e] + FLOOR_TERM;
        finalize_and_write(probs, cap,
                           out + (size_t)tokidx * NUM_E,
                           out + (size_t)NTOK * NUM_E + (size_t)tokidx * NUM_E);
    }
}

extern "C" void kernel_launch(void* const* d_in, const int* in_sizes, int n_in,
                              void* d_out, int out_size, void* d_ws, size_t ws_size,
                              hipStream_t stream) {
    const float* tokens = (const float*)d_in[0];
    const int*   ttypes = (const int*)d_in[1];
    const int*   tarr   = (const int*)d_in[2];
    const float* W1     = (const float*)d_in[3];
    const float* b1     = (const float*)d_in[4];
    const float* W2     = (const float*)d_in[5];
    const float* b2     = (const float*)d_in[6];
    const float* base   = (const float*)d_in[7];
    float* out = (float*)d_out;

    int* cnt  = (int*)d_ws;
    int* list = (int*)d_ws + 64;   // 256 B offset; list worst case 128 KB

    hipMemsetAsync(cnt, 0, sizeof(int), stream);
    classify_kernel<<<NTOK / 256, 256, 0, stream>>>(ttypes, tarr, base, out, cnt, list);
    mlp_kernel<<<NTOK / GRP, 512, 0, stream>>>(tokens, tarr, W1, b1, W2, b2,
                                               out, cnt, list);
}